// Round 5
// baseline (1414.905 us; speedup 1.0000x reference)
//
#include <hip/hip_runtime.h>

// GraphGCN, R4: coarse bucket sort (128 dst-nodes/bucket) + LDS-accumulator
// aggregation. No per-edge global atomics anywhere:
//   count_kernel: per-block LDS hist -> 1 global atomic per (block,bucket)
//   scan_kernel : 1024-wide LDS scan of bucket counts
//   fill_kernel : LDS cursors (seeded from bucketOffs+blockBase), writes one
//                 packed u32 record (src<<7 | dst&127) per edge
//   agg_kernel  : 1 workgroup per bucket; LDS acc[128][65] fp32; 16-lane
//                 groups gather feat rows (float4) and ds_add_f32 into acc;
//                 degree counted in LDS; normalize + (FINAL) skip-add fused.

#define BNODES   128
#define MAXBUCK  1024     // supports N <= 131072
#define CBLOCKS  128
#define CTHREADS 256

__global__ void count_kernel(const int* __restrict__ dst, int E, int nbuck,
                             int* __restrict__ gcount, int* __restrict__ blockBase) {
    __shared__ int hist[MAXBUCK];
    for (int i = threadIdx.x; i < nbuck; i += blockDim.x) hist[i] = 0;
    __syncthreads();
    int per = (E + gridDim.x - 1) / gridDim.x;
    int beg = blockIdx.x * per;
    int end = min(E, beg + per);
    for (int e = beg + threadIdx.x; e < end; e += blockDim.x)
        atomicAdd(&hist[dst[e] >> 7], 1);
    __syncthreads();
    for (int i = threadIdx.x; i < nbuck; i += blockDim.x)
        blockBase[(size_t)blockIdx.x * nbuck + i] = atomicAdd(&gcount[i], hist[i]);
}

__global__ void scan_kernel(const int* __restrict__ gcount, int nbuck,
                            int* __restrict__ bucketOffs) {
    __shared__ int lds[MAXBUCK];
    int tid = threadIdx.x;
    lds[tid] = (tid < nbuck) ? gcount[tid] : 0;
    __syncthreads();
    for (int s = 1; s < MAXBUCK; s <<= 1) {
        int v = (tid >= s) ? lds[tid - s] : 0;
        __syncthreads();
        lds[tid] += v;
        __syncthreads();
    }
    if (tid < nbuck) bucketOffs[tid + 1] = lds[tid];
    if (tid == 0) bucketOffs[0] = 0;
}

__global__ void fill_kernel(const int* __restrict__ src, const int* __restrict__ dst,
                            int E, int nbuck,
                            const int* __restrict__ bucketOffs,
                            const int* __restrict__ blockBase,
                            unsigned int* __restrict__ recs) {
    __shared__ int cur[MAXBUCK];
    for (int i = threadIdx.x; i < nbuck; i += blockDim.x)
        cur[i] = bucketOffs[i] + blockBase[(size_t)blockIdx.x * nbuck + i];
    __syncthreads();
    int per = (E + gridDim.x - 1) / gridDim.x;
    int beg = blockIdx.x * per;
    int end = min(E, beg + per);
    for (int e = beg + threadIdx.x; e < end; e += blockDim.x) {
        int d = dst[e];
        int b = d >> 7;
        int pos = atomicAdd(&cur[b], 1);   // LDS atomic, on-CU
        recs[pos] = ((unsigned)src[e] << 7) | (unsigned)(d & 127);
    }
}

// One bucket per workgroup. 512 threads = 32 groups of 16 lanes; group
// processes edges k = gi, gi+32, ...; lane c owns float4 chunk c of the row.
template <int FINAL>
__launch_bounds__(512)
__global__ void agg_kernel(const float* __restrict__ xin,
                           const unsigned int* __restrict__ recs,
                           const int* __restrict__ bucketOffs,
                           const float* __restrict__ xskip,
                           float* __restrict__ outbuf, int N) {
    __shared__ float acc[BNODES * 65];   // stride 65: spreads rows across banks
    __shared__ int cnt[BNODES];
    int b = blockIdx.x;
    int lo = b << 7;
    int tid = threadIdx.x;
    for (int i = tid; i < BNODES * 65; i += blockDim.x) acc[i] = 0.f;
    for (int i = tid; i < BNODES; i += blockDim.x) cnt[i] = 0;
    __syncthreads();
    int beg = bucketOffs[b];
    int num = bucketOffs[b + 1] - beg;
    int gi = tid >> 4;
    int c4 = (tid & 15) * 4;
#pragma unroll 2
    for (int k = gi; k < num; k += 32) {
        unsigned rec = recs[beg + k];
        int s  = rec >> 7;
        int ld = rec & 127;
        const float4 v = *reinterpret_cast<const float4*>(xin + ((size_t)s << 6) + c4);
        atomicAdd(&acc[ld * 65 + c4 + 0], v.x);
        atomicAdd(&acc[ld * 65 + c4 + 1], v.y);
        atomicAdd(&acc[ld * 65 + c4 + 2], v.z);
        atomicAdd(&acc[ld * 65 + c4 + 3], v.w);
        if (c4 == 0) atomicAdd(&cnt[ld], 1);
    }
    __syncthreads();
    int nrows = min(BNODES, N - lo);
    for (int i = tid; i < nrows * 16; i += blockDim.x) {
        int r  = i >> 4;
        int cc = (i & 15) * 4;
        float inv = 1.0f / fmaxf((float)cnt[r], 1.0f);
        float4 o;
        o.x = acc[r * 65 + cc + 0] * inv;
        o.y = acc[r * 65 + cc + 1] * inv;
        o.z = acc[r * 65 + cc + 2] * inv;
        o.w = acc[r * 65 + cc + 3] * inv;
        if (FINAL) {
            const float4 xs = *reinterpret_cast<const float4*>(xskip + ((size_t)(lo + r) << 6) + cc);
            o.x = (xs.x + o.x) * 0.5f;
            o.y = (xs.y + o.y) * 0.5f;
            o.z = (xs.z + o.z) * 0.5f;
            o.w = (xs.w + o.w) * 0.5f;
        }
        *reinterpret_cast<float4*>(outbuf + ((size_t)(lo + r) << 6) + cc) = o;
    }
}

static inline size_t align_up(size_t x, size_t a) { return (x + a - 1) & ~(a - 1); }

extern "C" void kernel_launch(void* const* d_in, const int* in_sizes, int n_in,
                              void* d_out, int out_size, void* d_ws, size_t ws_size,
                              hipStream_t stream) {
    const float* feat = (const float*)d_in[0];
    const int*   src  = (const int*)d_in[1];
    const int*   dst  = (const int*)d_in[2];
    float* out = (float*)d_out;

    const int D = 64;
    int N = in_sizes[0] / D;              // 100000
    int E = in_sizes[1];                  // 1600000
    int nbuck = (N + BNODES - 1) / BNODES;  // 782

    // workspace layout
    char* ws = (char*)d_ws;
    size_t off = 0;
    float* buf_x = (float*)(ws + off);        off = align_up(off + (size_t)N * D * sizeof(float), 256);
    unsigned int* recs = (unsigned int*)(ws + off); off = align_up(off + (size_t)E * sizeof(unsigned int), 256);
    int* gcount    = (int*)(ws + off);        off = align_up(off + (size_t)MAXBUCK * sizeof(int), 256);
    int* bucketOffs= (int*)(ws + off);        off = align_up(off + (size_t)(MAXBUCK + 1) * sizeof(int), 256);
    int* blockBase = (int*)(ws + off);        off = align_up(off + (size_t)CBLOCKS * nbuck * sizeof(int), 256);
    (void)ws_size;

    hipMemsetAsync(gcount, 0, (size_t)MAXBUCK * sizeof(int), stream);

    count_kernel<<<CBLOCKS, CTHREADS, 0, stream>>>(dst, E, nbuck, gcount, blockBase);
    scan_kernel<<<1, MAXBUCK, 0, stream>>>(gcount, nbuck, bucketOffs);
    fill_kernel<<<CBLOCKS, CTHREADS, 0, stream>>>(src, dst, E, nbuck, bucketOffs, blockBase, recs);

    agg_kernel<0><<<nbuck, 512, 0, stream>>>(feat, recs, bucketOffs, nullptr, buf_x, N);
    agg_kernel<1><<<nbuck, 512, 0, stream>>>(buf_x, recs, bucketOffs, buf_x, out, N);
}

// Round 6
// 173.507 us; speedup vs baseline: 8.1548x; 8.1548x over previous
//
#include <hip/hip_runtime.h>

// GraphGCN R5: bucket front-end + per-bucket counting sort + gather agg.
//   count_kernel : per-block LDS hist over dst>>7 -> 1 global atomic/(block,bucket)
//   scan_kernel  : 1-block scan of 782 bucket counts -> bucketOffs
//   fill_kernel  : LDS cursors; writes packed rec (src<<7 | dst&127) per edge
//   sort_bucket  : 1 block/bucket; LDS hist+scan of local_dst -> writes offs[]
//                  and scatters edge_src within the bucket's contiguous window
//   agg_kernel   : R2 structure — 16 lanes per node row, register accumulate,
//                  one float4 store per lane; FINAL fuses (x + mean2)*0.5.
// Zero per-edge global atomics; all scattered stores land in 8KB L2-resident
// windows. recs overlays buf_x (dead before agg0 writes buf_x).

#define BNODES   128
#define MAXBUCK  1024     // supports N <= 131072
#define CBLOCKS  256
#define CTHREADS 256

__global__ void count_kernel(const int* __restrict__ dst, int E, int nbuck,
                             int* __restrict__ gcount, int* __restrict__ blockBase) {
    __shared__ int hist[MAXBUCK];
    for (int i = threadIdx.x; i < nbuck; i += blockDim.x) hist[i] = 0;
    __syncthreads();
    int per = (E + gridDim.x - 1) / gridDim.x;
    int beg = blockIdx.x * per;
    int end = min(E, beg + per);
    for (int e = beg + threadIdx.x; e < end; e += blockDim.x)
        atomicAdd(&hist[dst[e] >> 7], 1);
    __syncthreads();
    for (int i = threadIdx.x; i < nbuck; i += blockDim.x)
        blockBase[(size_t)blockIdx.x * nbuck + i] = atomicAdd(&gcount[i], hist[i]);
}

__global__ void scan_kernel(const int* __restrict__ gcount, int nbuck,
                            int* __restrict__ bucketOffs) {
    __shared__ int lds[MAXBUCK];
    int tid = threadIdx.x;
    lds[tid] = (tid < nbuck) ? gcount[tid] : 0;
    __syncthreads();
    for (int s = 1; s < MAXBUCK; s <<= 1) {
        int v = (tid >= s) ? lds[tid - s] : 0;
        __syncthreads();
        lds[tid] += v;
        __syncthreads();
    }
    if (tid < nbuck) bucketOffs[tid + 1] = lds[tid];
    if (tid == 0) bucketOffs[0] = 0;
}

__global__ void fill_kernel(const int* __restrict__ src, const int* __restrict__ dst,
                            int E, int nbuck,
                            const int* __restrict__ bucketOffs,
                            const int* __restrict__ blockBase,
                            unsigned int* __restrict__ recs) {
    __shared__ int cur[MAXBUCK];
    for (int i = threadIdx.x; i < nbuck; i += blockDim.x)
        cur[i] = bucketOffs[i] + blockBase[(size_t)blockIdx.x * nbuck + i];
    __syncthreads();
    int per = (E + gridDim.x - 1) / gridDim.x;
    int beg = blockIdx.x * per;
    int end = min(E, beg + per);
    for (int e = beg + threadIdx.x; e < end; e += blockDim.x) {
        int d = dst[e];
        int b = d >> 7;
        int pos = atomicAdd(&cur[b], 1);   // LDS atomic, on-CU
        recs[pos] = ((unsigned)src[e] << 7) | (unsigned)(d & 127);
    }
}

// One bucket per block: counting sort of recs by local_dst into edge_src,
// emitting offs[] (global CSR offsets) from the local exclusive scan.
__global__ void sort_bucket(const unsigned int* __restrict__ recs,
                            const int* __restrict__ bucketOffs, int nbuck, int N,
                            int* __restrict__ offs, int* __restrict__ edge_src) {
    __shared__ int hist[BNODES];
    __shared__ int sc[BNODES];
    __shared__ int cur[BNODES];
    int b = blockIdx.x;
    int tid = threadIdx.x;
    int beg = bucketOffs[b];
    int end = bucketOffs[b + 1];
    if (tid < BNODES) hist[tid] = 0;
    __syncthreads();
    for (int k = beg + tid; k < end; k += blockDim.x)
        atomicAdd(&hist[recs[k] & 127], 1);
    __syncthreads();
    if (tid < BNODES) sc[tid] = hist[tid];
    __syncthreads();
#pragma unroll
    for (int s = 1; s < BNODES; s <<= 1) {
        int v = (tid < BNODES && tid >= s) ? sc[tid - s] : 0;
        __syncthreads();
        if (tid < BNODES) sc[tid] += v;
        __syncthreads();
    }
    int lo = b << 7;
    if (tid < BNODES) {
        int excl = (tid == 0) ? 0 : sc[tid - 1];
        cur[tid] = excl;
        if (lo + tid < N) offs[lo + tid] = beg + excl;
    }
    if (b == nbuck - 1 && tid == 0) offs[N] = end;
    __syncthreads();
    for (int k = beg + tid; k < end; k += blockDim.x) {
        unsigned rec = recs[k];
        int ld = rec & 127;
        int pos = beg + atomicAdd(&cur[ld], 1);   // LDS cursor
        edge_src[pos] = (int)(rec >> 7);
    }
}

// One node row per 16 consecutive lanes; lane c owns float4 chunk c.
// FINAL=0: out = acc*inv.  FINAL=1: out = (xskip + acc*inv)*0.5.
template <int FINAL>
__launch_bounds__(256)
__global__ void agg_kernel(const float* __restrict__ xin,
                           const int* __restrict__ offs,
                           const int* __restrict__ edge_src,
                           const float* __restrict__ xskip,
                           float* __restrict__ outbuf, int N) {
    int t = blockIdx.x * blockDim.x + threadIdx.x;
    int n = t >> 4;
    int c = t & 15;
    if (n >= N) return;
    int beg = offs[n];
    int end = offs[n + 1];
    float ax = 0.f, ay = 0.f, az = 0.f, aw = 0.f;
    int k = beg;
    for (; k + 8 <= end; k += 8) {
        int s[8];
#pragma unroll
        for (int i = 0; i < 8; ++i) s[i] = edge_src[k + i];
#pragma unroll
        for (int i = 0; i < 8; ++i) {
            const float4 v = *reinterpret_cast<const float4*>(xin + ((size_t)s[i] << 6) + c * 4);
            ax += v.x; ay += v.y; az += v.z; aw += v.w;
        }
    }
    for (; k < end; ++k) {
        int s = edge_src[k];
        const float4 v = *reinterpret_cast<const float4*>(xin + ((size_t)s << 6) + c * 4);
        ax += v.x; ay += v.y; az += v.z; aw += v.w;
    }
    float inv = (end > beg) ? 1.0f / (float)(end - beg) : 0.0f;
    float4 r;
    if (FINAL) {
        const float4 xs = *reinterpret_cast<const float4*>(xskip + ((size_t)n << 6) + c * 4);
        r.x = (xs.x + ax * inv) * 0.5f;
        r.y = (xs.y + ay * inv) * 0.5f;
        r.z = (xs.z + az * inv) * 0.5f;
        r.w = (xs.w + aw * inv) * 0.5f;
    } else {
        r.x = ax * inv;
        r.y = ay * inv;
        r.z = az * inv;
        r.w = aw * inv;
    }
    *reinterpret_cast<float4*>(outbuf + ((size_t)n << 6) + c * 4) = r;
}

static inline size_t align_up(size_t x, size_t a) { return (x + a - 1) & ~(a - 1); }

extern "C" void kernel_launch(void* const* d_in, const int* in_sizes, int n_in,
                              void* d_out, int out_size, void* d_ws, size_t ws_size,
                              hipStream_t stream) {
    const float* feat = (const float*)d_in[0];
    const int*   src  = (const int*)d_in[1];
    const int*   dst  = (const int*)d_in[2];
    float* out = (float*)d_out;

    const int D = 64;
    int N = in_sizes[0] / D;                // 100000
    int E = in_sizes[1];                    // 1600000
    int nbuck = (N + BNODES - 1) / BNODES;  // 782

    // workspace layout; recs overlays buf_x (recs dead before agg0 writes buf_x)
    char* ws = (char*)d_ws;
    size_t off = 0;
    float* buf_x = (float*)(ws + off);  off = align_up(off + (size_t)N * D * sizeof(float), 256);
    int* edge_src  = (int*)(ws + off);  off = align_up(off + (size_t)E * sizeof(int), 256);
    int* offs      = (int*)(ws + off);  off = align_up(off + (size_t)(N + 1) * sizeof(int), 256);
    int* gcount    = (int*)(ws + off);  off = align_up(off + (size_t)MAXBUCK * sizeof(int), 256);
    int* bucketOffs= (int*)(ws + off);  off = align_up(off + (size_t)(MAXBUCK + 1) * sizeof(int), 256);
    int* blockBase = (int*)(ws + off);  off = align_up(off + (size_t)CBLOCKS * nbuck * sizeof(int), 256);
    unsigned int* recs = (unsigned int*)buf_x;   // overlay
    (void)ws_size;

    hipMemsetAsync(gcount, 0, (size_t)MAXBUCK * sizeof(int), stream);

    count_kernel<<<CBLOCKS, CTHREADS, 0, stream>>>(dst, E, nbuck, gcount, blockBase);
    scan_kernel<<<1, MAXBUCK, 0, stream>>>(gcount, nbuck, bucketOffs);
    fill_kernel<<<CBLOCKS, CTHREADS, 0, stream>>>(src, dst, E, nbuck, bucketOffs, blockBase, recs);
    sort_bucket<<<nbuck, 256, 0, stream>>>(recs, bucketOffs, nbuck, N, offs, edge_src);

    int grid_a = (N * 16 + 255) / 256;
    agg_kernel<0><<<grid_a, 256, 0, stream>>>(feat, offs, edge_src, nullptr, buf_x, N);
    agg_kernel<1><<<grid_a, 256, 0, stream>>>(buf_x, offs, edge_src, buf_x, out, N);
}

// Round 8
// 138.099 us; speedup vs baseline: 10.2456x; 1.2564x over previous
//
#include <hip/hip_runtime.h>

// GraphGCN R7 (= R6 with compile fix): R5 pipeline + bf16 gather tables
// (f32 accumulate). NT stores now use clang ext_vector_type (HIP_vector_type
// is rejected by __builtin_nontemporal_store).
//   convert_kernel: feat (f32) -> feat_h (bf16 RN), 12.8MB table
//   count/scan/fill/sort: R5 bucket front-end (LDS cursors, no per-edge
//     global atomics)
//   agg<0>: gathers feat_h, mean in f32, writes buf_xh (bf16, nt-store)
//   agg<1>: gathers buf_xh, mean in f32, skip-adds bdec(buf_xh), out f32
// Gather demand halves (410->205MB) and the 12.8MB table doubles its L2 hit
// rate; nt stores keep the output stream from evicting the gather table.

#define BNODES   128
#define MAXBUCK  1024     // supports N <= 131072
#define CBLOCKS  512
#define CTHREADS 256

typedef float v4f __attribute__((ext_vector_type(4)));
typedef unsigned short v4h __attribute__((ext_vector_type(4)));

__device__ __forceinline__ float bdec(unsigned short h) {
    union { unsigned u; float f; } x;
    x.u = (unsigned)h << 16;
    return x.f;
}
__device__ __forceinline__ unsigned short benc(float f) {
    union { float f; unsigned u; } x;
    x.f = f;
    unsigned u = x.u;
    return (unsigned short)((u + 0x7FFFu + ((u >> 16) & 1u)) >> 16);  // RN-even
}

__global__ void convert_kernel(const float* __restrict__ in,
                               unsigned short* __restrict__ outh, int total4) {
    int stride = gridDim.x * blockDim.x;
    for (int t = blockIdx.x * blockDim.x + threadIdx.x; t < total4; t += stride) {
        const float4 v = *reinterpret_cast<const float4*>(in + (size_t)t * 4);
        v4h h;
        h.x = benc(v.x); h.y = benc(v.y); h.z = benc(v.z); h.w = benc(v.w);
        __builtin_nontemporal_store(h, reinterpret_cast<v4h*>(outh + (size_t)t * 4));
    }
}

__global__ void count_kernel(const int* __restrict__ dst, int E, int nbuck,
                             int* __restrict__ gcount, int* __restrict__ blockBase) {
    __shared__ int hist[MAXBUCK];
    for (int i = threadIdx.x; i < nbuck; i += blockDim.x) hist[i] = 0;
    __syncthreads();
    int per = (E + gridDim.x - 1) / gridDim.x;
    int beg = blockIdx.x * per;
    int end = min(E, beg + per);
    for (int e = beg + threadIdx.x; e < end; e += blockDim.x)
        atomicAdd(&hist[dst[e] >> 7], 1);
    __syncthreads();
    for (int i = threadIdx.x; i < nbuck; i += blockDim.x)
        blockBase[(size_t)blockIdx.x * nbuck + i] = atomicAdd(&gcount[i], hist[i]);
}

__global__ void scan_kernel(const int* __restrict__ gcount, int nbuck,
                            int* __restrict__ bucketOffs) {
    __shared__ int lds[MAXBUCK];
    int tid = threadIdx.x;
    lds[tid] = (tid < nbuck) ? gcount[tid] : 0;
    __syncthreads();
    for (int s = 1; s < MAXBUCK; s <<= 1) {
        int v = (tid >= s) ? lds[tid - s] : 0;
        __syncthreads();
        lds[tid] += v;
        __syncthreads();
    }
    if (tid < nbuck) bucketOffs[tid + 1] = lds[tid];
    if (tid == 0) bucketOffs[0] = 0;
}

__global__ void fill_kernel(const int* __restrict__ src, const int* __restrict__ dst,
                            int E, int nbuck,
                            const int* __restrict__ bucketOffs,
                            const int* __restrict__ blockBase,
                            unsigned int* __restrict__ recs) {
    __shared__ int cur[MAXBUCK];
    for (int i = threadIdx.x; i < nbuck; i += blockDim.x)
        cur[i] = bucketOffs[i] + blockBase[(size_t)blockIdx.x * nbuck + i];
    __syncthreads();
    int per = (E + gridDim.x - 1) / gridDim.x;
    int beg = blockIdx.x * per;
    int end = min(E, beg + per);
    for (int e = beg + threadIdx.x; e < end; e += blockDim.x) {
        int d = dst[e];
        int b = d >> 7;
        int pos = atomicAdd(&cur[b], 1);   // LDS atomic, on-CU
        recs[pos] = ((unsigned)src[e] << 7) | (unsigned)(d & 127);
    }
}

// One bucket per block: counting sort of recs by local_dst into edge_src,
// emitting offs[] (global CSR offsets) from the local exclusive scan.
__global__ void sort_bucket(const unsigned int* __restrict__ recs,
                            const int* __restrict__ bucketOffs, int nbuck, int N,
                            int* __restrict__ offs, int* __restrict__ edge_src) {
    __shared__ int hist[BNODES];
    __shared__ int sc[BNODES];
    __shared__ int cur[BNODES];
    int b = blockIdx.x;
    int tid = threadIdx.x;
    int beg = bucketOffs[b];
    int end = bucketOffs[b + 1];
    if (tid < BNODES) hist[tid] = 0;
    __syncthreads();
    for (int k = beg + tid; k < end; k += blockDim.x)
        atomicAdd(&hist[recs[k] & 127], 1);
    __syncthreads();
    if (tid < BNODES) sc[tid] = hist[tid];
    __syncthreads();
#pragma unroll
    for (int s = 1; s < BNODES; s <<= 1) {
        int v = (tid < BNODES && tid >= s) ? sc[tid - s] : 0;
        __syncthreads();
        if (tid < BNODES) sc[tid] += v;
        __syncthreads();
    }
    int lo = b << 7;
    if (tid < BNODES) {
        int excl = (tid == 0) ? 0 : sc[tid - 1];
        cur[tid] = excl;
        if (lo + tid < N) offs[lo + tid] = beg + excl;
    }
    if (b == nbuck - 1 && tid == 0) offs[N] = end;
    __syncthreads();
    for (int k = beg + tid; k < end; k += blockDim.x) {
        unsigned rec = recs[k];
        int ld = rec & 127;
        int pos = beg + atomicAdd(&cur[ld], 1);   // LDS cursor
        edge_src[pos] = (int)(rec >> 7);
    }
}

// One node row per 16 consecutive lanes; lane c owns bf16x4 chunk c (8B).
// FINAL=0: buf_xh[n] = bf16(acc*inv)      (nt store)
// FINAL=1: out[n]    = (bdec(xskip) + acc*inv)*0.5   (f32, nt store)
template <int FINAL>
__launch_bounds__(256)
__global__ void agg_kernel(const unsigned short* __restrict__ xin,
                           const int* __restrict__ offs,
                           const int* __restrict__ edge_src,
                           unsigned short* __restrict__ outh,
                           float* __restrict__ outf, int N) {
    int t = blockIdx.x * blockDim.x + threadIdx.x;
    int n = t >> 4;
    int c = t & 15;
    if (n >= N) return;
    int beg = offs[n];
    int end = offs[n + 1];
    float ax = 0.f, ay = 0.f, az = 0.f, aw = 0.f;
    int k = beg;
    for (; k + 8 <= end; k += 8) {
        int s[8];
#pragma unroll
        for (int i = 0; i < 8; ++i) s[i] = edge_src[k + i];
#pragma unroll
        for (int i = 0; i < 8; ++i) {
            const ushort4 h = *reinterpret_cast<const ushort4*>(xin + ((size_t)s[i] << 6) + c * 4);
            ax += bdec(h.x); ay += bdec(h.y); az += bdec(h.z); aw += bdec(h.w);
        }
    }
    for (; k < end; ++k) {
        int s = edge_src[k];
        const ushort4 h = *reinterpret_cast<const ushort4*>(xin + ((size_t)s << 6) + c * 4);
        ax += bdec(h.x); ay += bdec(h.y); az += bdec(h.z); aw += bdec(h.w);
    }
    float inv = (end > beg) ? 1.0f / (float)(end - beg) : 0.0f;
    ax *= inv; ay *= inv; az *= inv; aw *= inv;
    if (FINAL) {
        const ushort4 hs = *reinterpret_cast<const ushort4*>(xin + ((size_t)n << 6) + c * 4);
        v4f r;
        r.x = (bdec(hs.x) + ax) * 0.5f;
        r.y = (bdec(hs.y) + ay) * 0.5f;
        r.z = (bdec(hs.z) + az) * 0.5f;
        r.w = (bdec(hs.w) + aw) * 0.5f;
        __builtin_nontemporal_store(r, reinterpret_cast<v4f*>(outf + ((size_t)n << 6) + c * 4));
    } else {
        v4h h;
        h.x = benc(ax); h.y = benc(ay); h.z = benc(az); h.w = benc(aw);
        __builtin_nontemporal_store(h, reinterpret_cast<v4h*>(outh + ((size_t)n << 6) + c * 4));
    }
}

static inline size_t align_up(size_t x, size_t a) { return (x + a - 1) & ~(a - 1); }

extern "C" void kernel_launch(void* const* d_in, const int* in_sizes, int n_in,
                              void* d_out, int out_size, void* d_ws, size_t ws_size,
                              hipStream_t stream) {
    const float* feat = (const float*)d_in[0];
    const int*   src  = (const int*)d_in[1];
    const int*   dst  = (const int*)d_in[2];
    float* out = (float*)d_out;

    const int D = 64;
    int N = in_sizes[0] / D;                // 100000
    int E = in_sizes[1];                    // 1600000
    int nbuck = (N + BNODES - 1) / BNODES;  // 782

    // workspace layout
    //   recs overlays buf_xh (recs dead before agg0 writes buf_xh)
    //   blockBase overlays edge_src (blockBase dead before sort writes edge_src)
    char* ws = (char*)d_ws;
    size_t off = 0;
    unsigned short* feat_h = (unsigned short*)(ws + off); off = align_up(off + (size_t)N * D * sizeof(unsigned short), 256);
    unsigned short* buf_xh = (unsigned short*)(ws + off); off = align_up(off + (size_t)N * D * sizeof(unsigned short), 256);
    int* edge_src  = (int*)(ws + off);  off = align_up(off + (size_t)E * sizeof(int), 256);
    int* offs      = (int*)(ws + off);  off = align_up(off + (size_t)(N + 1) * sizeof(int), 256);
    int* gcount    = (int*)(ws + off);  off = align_up(off + (size_t)MAXBUCK * sizeof(int), 256);
    int* bucketOffs= (int*)(ws + off);  off = align_up(off + (size_t)(MAXBUCK + 1) * sizeof(int), 256);
    unsigned int* recs = (unsigned int*)buf_xh;   // overlay
    int* blockBase = edge_src;                    // overlay
    (void)ws_size;

    (void)hipMemsetAsync(gcount, 0, (size_t)MAXBUCK * sizeof(int), stream);

    int grid_c = (N * D / 4 + CTHREADS - 1) / CTHREADS;
    convert_kernel<<<min(grid_c, 2048), CTHREADS, 0, stream>>>(feat, feat_h, N * D / 4);
    count_kernel<<<CBLOCKS, CTHREADS, 0, stream>>>(dst, E, nbuck, gcount, blockBase);
    scan_kernel<<<1, MAXBUCK, 0, stream>>>(gcount, nbuck, bucketOffs);
    fill_kernel<<<CBLOCKS, CTHREADS, 0, stream>>>(src, dst, E, nbuck, bucketOffs, blockBase, recs);
    sort_bucket<<<nbuck, 256, 0, stream>>>(recs, bucketOffs, nbuck, N, offs, edge_src);

    int grid_a = (N * 16 + 255) / 256;
    agg_kernel<0><<<grid_a, 256, 0, stream>>>(feat_h, offs, edge_src, buf_xh, nullptr, N);
    agg_kernel<1><<<grid_a, 256, 0, stream>>>(buf_xh, offs, edge_src, nullptr, out, N);
}